// Round 17
// baseline (235.887 us; speedup 1.0000x reference)
//
#include <hip/hip_runtime.h>
#include <math.h>

#define NB   16
#define NN   16384
#define LDIM 512
#define DDIM 128
#define HIDD 128
#define NCLS 3
#define KCAP 256
#define CCAP 1024
#define ROWB 8
#define EPSV 1e-8f
#define DELTA 0.03f

typedef float  f32x4  __attribute__((ext_vector_type(4)));
typedef int    i32x4  __attribute__((ext_vector_type(4)));
typedef unsigned u32x2 __attribute__((ext_vector_type(2)));
typedef __bf16 bf16x8 __attribute__((ext_vector_type(8)));
typedef unsigned long long u64;

__device__ __forceinline__ int get_k(const int* kp) {
    int k = kp[0];
    if (k < 1 || k > NN) {
        float f = __int_as_float(k);
        if (f >= 1.0f && f <= (float)NN) k = (int)f;
        else k = 70;
    }
    if (k > NN) k = NN;
    return k;
}

__device__ __forceinline__ unsigned okey(float f) {
    unsigned u = __float_as_uint(f);
    return (u & 0x80000000u) ? ~u : (u | 0x80000000u);
}

// pack two fp32 -> two RNE bf16 in one u32 (a -> low, b -> high)  [r2/r3-proven]
__device__ __forceinline__ unsigned pk2bf(float a, float b) {
    unsigned ua = __float_as_uint(a); ua = (ua + 0x7FFFu + ((ua >> 16) & 1u)) >> 16;
    unsigned ub = __float_as_uint(b); ub = (ub + 0x7FFFu + ((ub >> 16) & 1u)) & 0xFFFF0000u;
    return (ua & 0xFFFFu) | ub;
}

__device__ __forceinline__ f32x4 mfma16(i32x4 a, i32x4 b, f32x4 c) {
    return __builtin_amdgcn_mfma_f32_16x16x32_bf16(
        __builtin_bit_cast(bf16x8, a), __builtin_bit_cast(bf16x8, b), c, 0, 0, 0);
}

__device__ __forceinline__ float sig_fast(float v)  { return 1.0f / (1.0f + __expf(-v)); }
__device__ __forceinline__ float tanh_fast(float v) { return 1.0f - 2.0f / (1.0f + __expf(2.0f * v)); }

// ---------------------------------------------------------------------------
// K0: swizzle Wv,Wu into bf16 FRAGMENT-LANE order (r2-proven)
// ---------------------------------------------------------------------------
__global__ void k0_prep(const float* __restrict__ Wv, const float* __restrict__ Wu,
                        unsigned short* __restrict__ Wp)
{
    int i = blockIdx.x * 256 + threadIdx.x;
    int g   = i >> 16;
    int rem = i & 65535;
    int kd  = rem >> 7;
    int n   = rem & 127;
    float w = g ? Wu[rem] : Wv[rem];
    unsigned u = __float_as_uint(w);
    u = (u + 0x7FFFu + ((u >> 16) & 1u)) >> 16;
    int kt = kd >> 5, lg = (kd >> 3) & 3, j = kd & 7, nt = n >> 4, lr = n & 15;
    Wp[kt * 8192 + g * 4096 + nt * 512 + lg * 128 + lr * 8 + j] = (unsigned short)u;
}

// ---------------------------------------------------------------------------
// K1 (r17): r16 kernel + DEPTH-2 x prefetch. Even tiles live in xgA, odd in
// xgB (parity static under unroll-2 -> no scratch). At tile j we issue loads
// for tile j+2; ds_write(j+1) consumes loads issued a full tile earlier, so
// it never stalls on HBM latency. Buffer hazards unchanged (one barrier/tile).
// ---------------------------------------------------------------------------
__global__ __launch_bounds__(512, 1)
void k1_mfma(const float* __restrict__ x, const unsigned short* __restrict__ Wp,
             const float* __restrict__ bv, const float* __restrict__ bu,
             const float* __restrict__ Wa, const float* __restrict__ ba,
             float* __restrict__ logits)
{
    __shared__ __align__(16) char lds[98304];  // buf0 32K | buf1 32K | sEp 32K

    const int t   = threadIdx.x;
    const int wid = t >> 6;
    const int l   = t & 63;
    const int lr  = l & 15;
    const int lg  = l >> 4;
    const int l7  = lr & 7;

    const int c     = t & 127;
    const int r0    = t >> 7;
    const int chalf = c & 1;
    const int clog  = c >> 1;

    const size_t blk_row0 = (size_t)blockIdx.x * 1024;
    const float* xblk = x + blk_row0 * LDIM;
    float* sEp = (float*)(lds + 65536);

    f32x4 acc[2][2];
    f32x4 xgA[8], xgB[8];

    // (1) issue tile-0 loads FIRST (HBM latency overlaps Wreg L2 preload)
#pragma unroll
    for (int i = 0; i < 8; ++i)
        xgA[i] = *(const f32x4*)(xblk + (size_t)(i * 4 + r0) * LDIM + c * 4);

    // (2) wave-resident weights from L2
    i32x4 Wreg[2][16];
    {
        const unsigned short* wb = Wp + wid * 512 + l * 8;
#pragma unroll
        for (int kt = 0; kt < 16; ++kt) {
#pragma unroll
            for (int g = 0; g < 2; ++g)
                Wreg[g][kt] = *(const i32x4*)(wb + kt * 8192 + g * 4096);
        }
    }

    const int dbase = wid * 16 + lg * 4;
    float bvR[4], buR[4], waR[4];
#pragma unroll
    for (int r = 0; r < 4; ++r) {
        bvR[r] = bv[dbase + r]; buR[r] = bu[dbase + r]; waR[r] = Wa[dbase + r];
    }
    const float ba0 = ba[0];

    // (3) pack + stage tile 0 from xgA
#pragma unroll
    for (int i = 0; i < 8; ++i) {
        int row = i * 4 + r0;
        u32x2 wv; wv.x = pk2bf(xgA[i].x, xgA[i].y); wv.y = pk2bf(xgA[i].z, xgA[i].w);
        *(u32x2*)(lds + row * 1024 + ((clog ^ (row & 7)) * 16) + chalf * 8) = wv;
    }
    // (4) issue tile-1 loads into xgB (lands during tile-0 compute)
    {
        const float* xt = xblk + (size_t)32 * LDIM;
#pragma unroll
        for (int i = 0; i < 8; ++i)
            xgB[i] = *(const f32x4*)(xt + (size_t)(i * 4 + r0) * LDIM + c * 4);
    }
    __syncthreads();

    int p = 0;
#pragma unroll 2
    for (int j = 0; j < 32; ++j) {
        // (1) issue tile j+2 loads into the set that held tile j (now dead):
        //     even j -> xgA, odd j -> xgB (parity static under unroll-2)
        if (j + 2 < 32) {
            const float* xt = xblk + (size_t)(j + 2) * 32 * LDIM;
            if ((j & 1) == 0) {
#pragma unroll
                for (int i = 0; i < 8; ++i)
                    xgA[i] = *(const f32x4*)(xt + (size_t)(i * 4 + r0) * LDIM + c * 4);
            } else {
#pragma unroll
                for (int i = 0; i < 8; ++i)
                    xgB[i] = *(const f32x4*)(xt + (size_t)(i * 4 + r0) * LDIM + c * 4);
            }
        }
        // (2) MFMA from buf p
#pragma unroll
        for (int g = 0; g < 2; ++g)
#pragma unroll
            for (int rf = 0; rf < 2; ++rf)
                acc[g][rf] = f32x4{0.f, 0.f, 0.f, 0.f};
        const char* Xb = lds + p * 32768;
#pragma unroll
        for (int kt = 0; kt < 16; ++kt) {
            i32x4 b0 = *(const i32x4*)(Xb + lr * 1024        + (((kt * 4 + lg) ^ l7) * 16));
            i32x4 b1 = *(const i32x4*)(Xb + (16 + lr) * 1024 + (((kt * 4 + lg) ^ l7) * 16));
            acc[0][0] = mfma16(Wreg[0][kt], b0, acc[0][0]);
            acc[1][0] = mfma16(Wreg[1][kt], b0, acc[1][0]);
            acc[0][1] = mfma16(Wreg[0][kt], b1, acc[0][1]);
            acc[1][1] = mfma16(Wreg[1][kt], b1, acc[1][1]);
        }
        // (3) pack + write tile j+1 (loaded a FULL tile ago -> no vmcnt stall):
        //     even j -> tile j+1 in xgB, odd j -> in xgA
        if (j + 1 < 32) {
            char* Xw = lds + (p ^ 1) * 32768;
            if ((j & 1) == 0) {
#pragma unroll
                for (int i = 0; i < 8; ++i) {
                    int row = i * 4 + r0;
                    u32x2 wv; wv.x = pk2bf(xgB[i].x, xgB[i].y); wv.y = pk2bf(xgB[i].z, xgB[i].w);
                    *(u32x2*)(Xw + row * 1024 + ((clog ^ (row & 7)) * 16) + chalf * 8) = wv;
                }
            } else {
#pragma unroll
                for (int i = 0; i < 8; ++i) {
                    int row = i * 4 + r0;
                    u32x2 wv; wv.x = pk2bf(xgA[i].x, xgA[i].y); wv.y = pk2bf(xgA[i].z, xgA[i].w);
                    *(u32x2*)(Xw + row * 1024 + ((clog ^ (row & 7)) * 16) + chalf * 8) = wv;
                }
            }
        }
        // (4) epilogue: per-tile partials to disjoint sEp slots
#pragma unroll
        for (int rf = 0; rf < 2; ++rf) {
            float s = 0.f;
#pragma unroll
            for (int r = 0; r < 4; ++r) {
                float vv = tanh_fast(acc[0][rf][r] + bvR[r]);
                float uu = sig_fast (acc[1][rf][r] + buR[r]);
                s = fmaf(vv * uu, waR[r], s);
            }
            s += __shfl_xor(s, 16);
            s += __shfl_xor(s, 32);
            if (l < 16) sEp[wid * 1024 + j * 32 + rf * 16 + l] = s;
        }
        __syncthreads();   // single barrier: publishes buf p^1, protects buf p
        p ^= 1;
    }

#pragma unroll
    for (int rr = 0; rr < 2; ++rr) {
        int row = t + rr * 512;
        float s = ba0;
#pragma unroll
        for (int w2 = 0; w2 < 8; ++w2) s += sEp[w2 * 1024 + row];
        logits[blk_row0 + row] = s;
    }
}

// ---------------------------------------------------------------------------
// K3a (r16-verified, verbatim): float-interval bisection band + softmax.
// ---------------------------------------------------------------------------
__global__ __launch_bounds__(512, 1)
void k3a_band_softmax(float* __restrict__ A, const float* __restrict__ mask,
                      const int* __restrict__ kp, int* __restrict__ idxWS,
                      int* __restrict__ candIdx, int* __restrict__ counts)
{
    __shared__ float sredf[2][8];
    __shared__ int   sredi[2][8];
    __shared__ int sIn, sCand;
    const int b = blockIdx.x;
    const int t = threadIdx.x;     // 0..511
    const int w = t >> 6;          // 0..7
    int k = get_k(kp); if (k > KCAP) k = KCAP;
    float* Ab = A + (size_t)b * NN;
    const float* mb = mask + (size_t)b * NN;

    float raw[32]; u64 mbits = 0ULL;
#pragma unroll
    for (int j = 0; j < 32; ++j) {
        int i = t + j * 512;
        raw[j] = Ab[i];
        if (mb[i] > 0.0f) mbits |= (1ULL << j);
    }

    float mxm = -3.0e38f;
#pragma unroll
    for (int j = 0; j < 32; ++j)
        if ((mbits >> j) & 1) mxm = fmaxf(mxm, raw[j]);
#pragma unroll
    for (int m2 = 1; m2 < 64; m2 <<= 1) mxm = fmaxf(mxm, __shfl_xor(mxm, m2));
    if ((t & 63) == 0) sredf[0][w] = mxm;
    __syncthreads();
    mxm = sredf[0][0];
#pragma unroll
    for (int w2 = 1; w2 < 8; ++w2) mxm = fmaxf(mxm, sredf[0][w2]);

    float lov = mxm - 32.0f, hiv = mxm;
    {
        int par = 0;
#pragma unroll
        for (int it = 0; it < 12; ++it) {
            float mid = 0.5f * (lov + hiv);
            int cgt = 0;
#pragma unroll
            for (int j = 0; j < 32; ++j) {
                float v = ((mbits >> j) & 1) ? raw[j] : -3.0e38f;
                cgt += (v >= mid) ? 1 : 0;
            }
#pragma unroll
            for (int m2 = 1; m2 < 64; m2 <<= 1) cgt += __shfl_xor(cgt, m2);
            if ((t & 63) == 0) sredi[par][w] = cgt;
            __syncthreads();
            cgt = 0;
#pragma unroll
            for (int w2 = 0; w2 < 8; ++w2) cgt += sredi[par][w2];
            if (cgt >= k) lov = mid; else hiv = mid;
            par ^= 1;
        }
    }
    const float tv = lov;

    if (t == 0) { sIn = 0; sCand = 0; }
    __syncthreads();
    const float hiB = tv + DELTA, loB = tv - DELTA;
#pragma unroll
    for (int j = 0; j < 32; ++j) {
        int i = t + j * 512;
        float v = ((mbits >> j) & 1) ? raw[j] : -3.0e38f;
        if (v > hiB)       { int p = atomicAdd(&sIn, 1);   if (p < KCAP) idxWS[b * KCAP + p] = i; }
        else if (v >= loB) { int p = atomicAdd(&sCand, 1); if (p < CCAP) candIdx[b * CCAP + p] = i; }
    }

    float mx = -INFINITY;
#pragma unroll
    for (int j = 0; j < 32; ++j) mx = fmaxf(mx, raw[j]);
#pragma unroll
    for (int m2 = 1; m2 < 64; m2 <<= 1) mx = fmaxf(mx, __shfl_xor(mx, m2));
    __syncthreads();
    if ((t & 63) == 0) sredf[1][w] = mx;
    __syncthreads();
    mx = sredf[1][0];
#pragma unroll
    for (int w2 = 1; w2 < 8; ++w2) mx = fmaxf(mx, sredf[1][w2]);

    float sAll = 0.f, sM = 0.f;
#pragma unroll
    for (int j = 0; j < 32; ++j) {
        float e = __expf(raw[j] - mx);
        sAll += e;
        if ((mbits >> j) & 1) sM += e;
    }
#pragma unroll
    for (int m2 = 1; m2 < 64; m2 <<= 1) sAll += __shfl_xor(sAll, m2);
    __syncthreads();
    if ((t & 63) == 0) sredf[0][w] = sAll;
    __syncthreads();
    sAll = 0.f;
#pragma unroll
    for (int w2 = 0; w2 < 8; ++w2) sAll += sredf[0][w2];
#pragma unroll
    for (int m2 = 1; m2 < 64; m2 <<= 1) sM += __shfl_xor(sM, m2);
    __syncthreads();
    if ((t & 63) == 0) sredf[1][w] = sM;
    __syncthreads();
    sM = 0.f;
#pragma unroll
    for (int w2 = 0; w2 < 8; ++w2) sM += sredf[1][w2];

    const float inv = 1.0f / (sM + EPSV * sAll);
#pragma unroll
    for (int j = 0; j < 32; ++j) {
        int i = t + j * 512;
        float e = __expf(raw[j] - mx);
        Ab[i] = ((mbits >> j) & 1) ? e * inv : 0.0f;
    }
    if (t == 0) {
        int m1 = sIn;   if (m1 > k)    m1 = k;
        int cc = sCand; if (cc > CCAP) cc = CCAP;
        counts[b * 4]     = m1;
        counts[b * 4 + 1] = cc;
    }
}

// ---------------------------------------------------------------------------
// K3b (r15-verified, verbatim): 512 thr; thread = (d, ll-quarter).
// ---------------------------------------------------------------------------
__global__ __launch_bounds__(512)
void k3b_exact(const float* __restrict__ x,
               const float* __restrict__ Wv, const float* __restrict__ bv,
               const float* __restrict__ Wu, const float* __restrict__ bu,
               const float* __restrict__ Wa, const float* __restrict__ ba,
               const int* __restrict__ candIdx, const int* __restrict__ counts,
               float* __restrict__ candVal)
{
    __shared__ __align__(16) float sx[ROWB][LDIM];      // 16 KB
    __shared__ float sqv[4][ROWB][DDIM];                // 16 KB
    __shared__ float squ[4][ROWB][DDIM];                // 16 KB
    __shared__ float sred[2][ROWB];
    const int b = blockIdx.x;
    const int t = threadIdx.x;      // 0..511
    const int d = t & 127;
    const int q = t >> 7;           // 0..3
    const int cnt = counts[b * 4 + 1];
    const float ba0 = ba[0];

    for (int base = blockIdx.y * ROWB; base < cnt; base += gridDim.y * ROWB) {
        const int nr = min(ROWB, cnt - base);
#pragma unroll
        for (int rr = 0; rr < 2; ++rr) {
            int idx = t + rr * 512;
            int r   = idx >> 7;
            int c4  = idx & 127;
            int rowi = (r < nr) ? (base + r) : base;
            const int row = candIdx[b * CCAP + rowi];
            ((f32x4*)&sx[r][0])[c4] =
                ((const f32x4*)(x + ((size_t)b * NN + (size_t)row) * LDIM))[c4];
        }
        __syncthreads();

        float dv[ROWB], du[ROWB];
#pragma unroll
        for (int r = 0; r < ROWB; ++r) { dv[r] = 0.f; du[r] = 0.f; }
        const int ll0 = q * 128;
#pragma unroll 4
        for (int l2 = 0; l2 < 128; ++l2) {
            const int ll = ll0 + l2;
            const float wvl = Wv[ll * DDIM + d];
            const float wul = Wu[ll * DDIM + d];
#pragma unroll
            for (int r = 0; r < ROWB; ++r) {
                const float xv = sx[r][ll];
                dv[r] = fmaf(xv, wvl, dv[r]);
                du[r] = fmaf(xv, wul, du[r]);
            }
        }
#pragma unroll
        for (int r = 0; r < ROWB; ++r) { sqv[q][r][d] = dv[r]; squ[q][r][d] = du[r]; }
        __syncthreads();

        if (q == 0) {
            const float bvd = bv[d], bud = bu[d], wad = Wa[d];
            const int w2 = t >> 6;   // 0/1
#pragma unroll
            for (int r = 0; r < ROWB; ++r) {
                float fv = sqv[0][r][d] + sqv[1][r][d] + sqv[2][r][d] + sqv[3][r][d] + bvd;
                float fu = squ[0][r][d] + squ[1][r][d] + squ[2][r][d] + squ[3][r][d] + bud;
                float c = tanhf(fv) * (1.0f / (1.0f + expf(-fu))) * wad;
                c += __shfl_xor(c, 1);  c += __shfl_xor(c, 2);
                c += __shfl_xor(c, 4);  c += __shfl_xor(c, 8);
                c += __shfl_xor(c, 16); c += __shfl_xor(c, 32);
                if ((t & 63) == 0) sred[w2][r] = c;
            }
        }
        __syncthreads();
        if (t < nr) candVal[b * CCAP + base + t] = sred[0][t] + sred[1][t] + ba0;
        __syncthreads();
    }
}

// ---------------------------------------------------------------------------
// K34 (r15-verified, verbatim): 512 threads; coalesced pooling; split MLP.
// ---------------------------------------------------------------------------
__global__ __launch_bounds__(512)
void k34_select_final(const float* __restrict__ x, const int* __restrict__ kp,
                      const int* __restrict__ candIdx, const float* __restrict__ candVal,
                      const int* __restrict__ counts, const int* __restrict__ idxWS,
                      const float* __restrict__ W1, const float* __restrict__ b1,
                      const float* __restrict__ W2, const float* __restrict__ b2,
                      float* __restrict__ Yprob, float* __restrict__ Yhat)
{
    __shared__ u64 keys[CCAP];
    __shared__ int sIdx[KCAP];
    __shared__ int sFinal[KCAP];
    __shared__ int sPos;
    __shared__ float sPooled[LDIM];
    __shared__ float sHp[4][HIDD];
    __shared__ float sH[HIDD];
    __shared__ float sY[4];
    const int b = blockIdx.x;
    const int t = threadIdx.x;      // 0..511
    int k = get_k(kp); if (k > KCAP) k = KCAP;
    const int m1  = counts[b * 4];
    const int cnt = counts[b * 4 + 1];
    int need = k - m1; if (need < 0) need = 0; if (need > cnt) need = cnt;

    for (int i = t; i < cnt; i += 512)
        keys[i] = (((u64)okey(candVal[b * CCAP + i])) << 14)
                | (u64)(16383 - candIdx[b * CCAP + i]);
    if (t < m1) sIdx[t] = idxWS[b * KCAP + t];
    if (t == 0) sPos = 0;
    if (t < KCAP) sFinal[t] = 0;
    __syncthreads();
    for (int i = t; i < cnt; i += 512) {
        u64 mk = keys[i];
        int rank = 0;
        for (int j = 0; j < cnt; ++j) rank += (keys[j] > mk) ? 1 : 0;
        if (rank < need) { int p = atomicAdd(&sPos, 1); sIdx[m1 + p] = candIdx[b * CCAP + i]; }
    }
    __syncthreads();
    int tot = m1 + need; if (tot > k) tot = k;
    if (t < tot) {
        int myv = sIdx[t];
        int rank = 0;
        for (int e = 0; e < tot; ++e) rank += (sIdx[e] < myv) ? 1 : 0;
        sFinal[rank] = myv;
    }
    __syncthreads();

    {
        float a0 = 0.0f;
        int j = 0;
        for (; j + 8 <= k; j += 8) {
            float t0[8];
#pragma unroll
            for (int u2 = 0; u2 < 8; ++u2)
                t0[u2] = x[((size_t)b * NN + (size_t)sFinal[j + u2]) * LDIM + t];
#pragma unroll
            for (int u2 = 0; u2 < 8; ++u2) a0 += t0[u2];
        }
        for (; j < k; ++j)
            a0 += x[((size_t)b * NN + (size_t)sFinal[j]) * LDIM + t];
        sPooled[t] = a0 * (1.0f / (float)k);
    }
    __syncthreads();

    {
        const int d = t & 127;
        const int q = t >> 7;
        float acc = 0.f;
#pragma unroll 4
        for (int l2 = 0; l2 < 128; ++l2) {
            int ll = q * 128 + l2;
            acc = fmaf(sPooled[ll], W1[ll * HIDD + d], acc);
        }
        sHp[q][d] = acc;
    }
    __syncthreads();
    if (t < HIDD) {
        float acc = b1[t] + sHp[0][t] + sHp[1][t] + sHp[2][t] + sHp[3][t];
        sH[t] = fmaxf(acc, 0.0f);
    }
    __syncthreads();
    if (t < NCLS) {
        float y = b2[t];
        for (int hh = 0; hh < HIDD; ++hh) y = fmaf(sH[hh], W2[hh * NCLS + t], y);
        Yprob[b * NCLS + t] = y;
        sY[t] = y;
    }
    __syncthreads();
    if (t == 0) {
        int am = 0; float bst = sY[0];
        if (sY[1] > bst) { bst = sY[1]; am = 1; }
        if (sY[2] > bst) { bst = sY[2]; am = 2; }
        Yhat[b] = (float)am;
    }
}

// ---------------------------------------------------------------------------
extern "C" void kernel_launch(void* const* d_in, const int* in_sizes, int n_in,
                              void* d_out, int out_size, void* d_ws, size_t ws_size,
                              hipStream_t stream)
{
    const float* x    = (const float*)d_in[0];
    const float* mask = (const float*)d_in[1];
    const float* Wv   = (const float*)d_in[2];
    const float* bv   = (const float*)d_in[3];
    const float* Wu   = (const float*)d_in[4];
    const float* bu   = (const float*)d_in[5];
    const float* Wa   = (const float*)d_in[6];
    const float* ba   = (const float*)d_in[7];
    const float* W1   = (const float*)d_in[8];
    const float* b1   = (const float*)d_in[9];
    const float* W2   = (const float*)d_in[10];
    const float* b2   = (const float*)d_in[11];
    const int*   kp   = (const int*)d_in[12];

    float* out   = (float*)d_out;
    float* Yprob = out;        // [16,3] = 48
    float* Yhat  = out + 48;   // [16]
    float* A     = out + 64;   // [16,16384]  (logits first, softmax in-place)

    char* wsb = (char*)d_ws;
    unsigned short* Wp = (unsigned short*)wsb;        // 256 KB
    int*   idxWS   = (int*)  (wsb + 262144);
    int*   candIdx = (int*)  (wsb + 278528);
    float* candVal = (float*)(wsb + 344064);
    int*   counts  = (int*)  (wsb + 409600);

    k0_prep  <<<512, 256, 0, stream>>>(Wv, Wu, Wp);
    k1_mfma  <<<256, 512, 0, stream>>>(x, Wp, bv, bu, Wa, ba, A);
    k3a_band_softmax<<<NB, 512, 0, stream>>>(A, mask, kp, idxWS, candIdx, counts);
    k3b_exact<<<dim3(NB, 32), 512, 0, stream>>>(x, Wv, bv, Wu, bu, Wa, ba,
                                                candIdx, counts, candVal);
    k34_select_final<<<NB, 512, 0, stream>>>(x, kp, candIdx, candVal, counts, idxWS,
                                             W1, b1, W2, b2, Yprob, Yhat);
}

// Round 18
// 191.666 us; speedup vs baseline: 1.2307x; 1.2307x over previous
//
#include <hip/hip_runtime.h>
#include <math.h>

#define NB   16
#define NN   16384
#define LDIM 512
#define DDIM 128
#define HIDD 128
#define NCLS 3
#define KCAP 256
#define CCAP 1024
#define ROWB 8
#define EPSV 1e-8f
#define DELTA 0.03f

typedef float  f32x4  __attribute__((ext_vector_type(4)));
typedef int    i32x4  __attribute__((ext_vector_type(4)));
typedef unsigned u32x2 __attribute__((ext_vector_type(2)));
typedef __bf16 bf16x8 __attribute__((ext_vector_type(8)));
typedef unsigned long long u64;

__device__ __forceinline__ int get_k(const int* kp) {
    int k = kp[0];
    if (k < 1 || k > NN) {
        float f = __int_as_float(k);
        if (f >= 1.0f && f <= (float)NN) k = (int)f;
        else k = 70;
    }
    if (k > NN) k = NN;
    return k;
}

__device__ __forceinline__ unsigned okey(float f) {
    unsigned u = __float_as_uint(f);
    return (u & 0x80000000u) ? ~u : (u | 0x80000000u);
}

// pack two fp32 -> two RNE bf16 in one u32 (a -> low, b -> high)  [r2/r3-proven]
__device__ __forceinline__ unsigned pk2bf(float a, float b) {
    unsigned ua = __float_as_uint(a); ua = (ua + 0x7FFFu + ((ua >> 16) & 1u)) >> 16;
    unsigned ub = __float_as_uint(b); ub = (ub + 0x7FFFu + ((ub >> 16) & 1u)) & 0xFFFF0000u;
    return (ua & 0xFFFFu) | ub;
}

__device__ __forceinline__ f32x4 mfma16(i32x4 a, i32x4 b, f32x4 c) {
    return __builtin_amdgcn_mfma_f32_16x16x32_bf16(
        __builtin_bit_cast(bf16x8, a), __builtin_bit_cast(bf16x8, b), c, 0, 0, 0);
}

__device__ __forceinline__ float sig_fast(float v)  { return 1.0f / (1.0f + __expf(-v)); }
__device__ __forceinline__ float tanh_fast(float v) { return 1.0f - 2.0f / (1.0f + __expf(2.0f * v)); }

// ---------------------------------------------------------------------------
// K0: swizzle Wv,Wu into bf16 FRAGMENT-LANE order (r2-proven)
// ---------------------------------------------------------------------------
__global__ void k0_prep(const float* __restrict__ Wv, const float* __restrict__ Wu,
                        unsigned short* __restrict__ Wp)
{
    int i = blockIdx.x * 256 + threadIdx.x;
    int g   = i >> 16;
    int rem = i & 65535;
    int kd  = rem >> 7;
    int n   = rem & 127;
    float w = g ? Wu[rem] : Wv[rem];
    unsigned u = __float_as_uint(w);
    u = (u + 0x7FFFu + ((u >> 16) & 1u)) >> 16;
    int kt = kd >> 5, lg = (kd >> 3) & 3, j = kd & 7, nt = n >> 4, lr = n & 15;
    Wp[kt * 8192 + g * 4096 + nt * 512 + lg * 128 + lr * 8 + j] = (unsigned short)u;
}

// ---------------------------------------------------------------------------
// K1 (r16-verified, 193us total config): operand-swapped MFMA, one barrier per
// j-tile, single-set depth-1 prefetch, x prologue loads issued before the
// Wreg L2 preload. (r17's depth-2 prefetch REGRESSED -- register cliff.)
// ---------------------------------------------------------------------------
__global__ __launch_bounds__(512, 1)
void k1_mfma(const float* __restrict__ x, const unsigned short* __restrict__ Wp,
             const float* __restrict__ bv, const float* __restrict__ bu,
             const float* __restrict__ Wa, const float* __restrict__ ba,
             float* __restrict__ logits)
{
    __shared__ __align__(16) char lds[98304];  // buf0 32K | buf1 32K | sEp 32K

    const int t   = threadIdx.x;
    const int wid = t >> 6;
    const int l   = t & 63;
    const int lr  = l & 15;
    const int lg  = l >> 4;
    const int l7  = lr & 7;

    const int c     = t & 127;
    const int r0    = t >> 7;
    const int chalf = c & 1;
    const int clog  = c >> 1;

    const size_t blk_row0 = (size_t)blockIdx.x * 1024;
    const float* xblk = x + blk_row0 * LDIM;
    float* sEp = (float*)(lds + 65536);

    f32x4 acc[2][2];
    f32x4 xg[8];

    // (1) issue prologue x loads FIRST (HBM latency overlaps Wreg L2 preload)
#pragma unroll
    for (int i = 0; i < 8; ++i)
        xg[i] = *(const f32x4*)(xblk + (size_t)(i * 4 + r0) * LDIM + c * 4);

    // (2) wave-resident weights from L2
    i32x4 Wreg[2][16];
    {
        const unsigned short* wb = Wp + wid * 512 + l * 8;
#pragma unroll
        for (int kt = 0; kt < 16; ++kt) {
#pragma unroll
            for (int g = 0; g < 2; ++g)
                Wreg[g][kt] = *(const i32x4*)(wb + kt * 8192 + g * 4096);
        }
    }

    const int dbase = wid * 16 + lg * 4;
    float bvR[4], buR[4], waR[4];
#pragma unroll
    for (int r = 0; r < 4; ++r) {
        bvR[r] = bv[dbase + r]; buR[r] = bu[dbase + r]; waR[r] = Wa[dbase + r];
    }
    const float ba0 = ba[0];

    // (3) pack + stage tile 0
#pragma unroll
    for (int i = 0; i < 8; ++i) {
        int row = i * 4 + r0;
        u32x2 wv; wv.x = pk2bf(xg[i].x, xg[i].y); wv.y = pk2bf(xg[i].z, xg[i].w);
        *(u32x2*)(lds + row * 1024 + ((clog ^ (row & 7)) * 16) + chalf * 8) = wv;
    }
    __syncthreads();

    int p = 0;
    for (int j = 0; j < 32; ++j) {
        const bool has_next = (j < 31);
        if (has_next) {
            const float* xt = xblk + (size_t)(j + 1) * 32 * LDIM;
#pragma unroll
            for (int i = 0; i < 8; ++i)
                xg[i] = *(const f32x4*)(xt + (size_t)(i * 4 + r0) * LDIM + c * 4);
        }
#pragma unroll
        for (int g = 0; g < 2; ++g)
#pragma unroll
            for (int rf = 0; rf < 2; ++rf)
                acc[g][rf] = f32x4{0.f, 0.f, 0.f, 0.f};
        const char* Xb = lds + p * 32768;
#pragma unroll
        for (int kt = 0; kt < 16; ++kt) {
            i32x4 b0 = *(const i32x4*)(Xb + lr * 1024        + (((kt * 4 + lg) ^ l7) * 16));
            i32x4 b1 = *(const i32x4*)(Xb + (16 + lr) * 1024 + (((kt * 4 + lg) ^ l7) * 16));
            acc[0][0] = mfma16(Wreg[0][kt], b0, acc[0][0]);
            acc[1][0] = mfma16(Wreg[1][kt], b0, acc[1][0]);
            acc[0][1] = mfma16(Wreg[0][kt], b1, acc[0][1]);
            acc[1][1] = mfma16(Wreg[1][kt], b1, acc[1][1]);
        }
        if (has_next) {
            char* Xw = lds + (p ^ 1) * 32768;
#pragma unroll
            for (int i = 0; i < 8; ++i) {
                int row = i * 4 + r0;
                u32x2 wv; wv.x = pk2bf(xg[i].x, xg[i].y); wv.y = pk2bf(xg[i].z, xg[i].w);
                *(u32x2*)(Xw + row * 1024 + ((clog ^ (row & 7)) * 16) + chalf * 8) = wv;
            }
        }
#pragma unroll
        for (int rf = 0; rf < 2; ++rf) {
            float s = 0.f;
#pragma unroll
            for (int r = 0; r < 4; ++r) {
                float vv = tanh_fast(acc[0][rf][r] + bvR[r]);
                float uu = sig_fast (acc[1][rf][r] + buR[r]);
                s = fmaf(vv * uu, waR[r], s);
            }
            s += __shfl_xor(s, 16);
            s += __shfl_xor(s, 32);
            if (l < 16) sEp[wid * 1024 + j * 32 + rf * 16 + l] = s;
        }
        __syncthreads();
        p ^= 1;
    }

#pragma unroll
    for (int rr = 0; rr < 2; ++rr) {
        int row = t + rr * 512;
        float s = ba0;
#pragma unroll
        for (int w2 = 0; w2 < 8; ++w2) s += sEp[w2 * 1024 + row];
        logits[blk_row0 + row] = s;
    }
}

// ---------------------------------------------------------------------------
// K3a (r16-verified, verbatim): float-interval bisection band + softmax.
// ---------------------------------------------------------------------------
__global__ __launch_bounds__(512, 1)
void k3a_band_softmax(float* __restrict__ A, const float* __restrict__ mask,
                      const int* __restrict__ kp, int* __restrict__ idxWS,
                      int* __restrict__ candIdx, int* __restrict__ counts)
{
    __shared__ float sredf[2][8];
    __shared__ int   sredi[2][8];
    __shared__ int sIn, sCand;
    const int b = blockIdx.x;
    const int t = threadIdx.x;     // 0..511
    const int w = t >> 6;          // 0..7
    int k = get_k(kp); if (k > KCAP) k = KCAP;
    float* Ab = A + (size_t)b * NN;
    const float* mb = mask + (size_t)b * NN;

    float raw[32]; u64 mbits = 0ULL;
#pragma unroll
    for (int j = 0; j < 32; ++j) {
        int i = t + j * 512;
        raw[j] = Ab[i];
        if (mb[i] > 0.0f) mbits |= (1ULL << j);
    }

    float mxm = -3.0e38f;
#pragma unroll
    for (int j = 0; j < 32; ++j)
        if ((mbits >> j) & 1) mxm = fmaxf(mxm, raw[j]);
#pragma unroll
    for (int m2 = 1; m2 < 64; m2 <<= 1) mxm = fmaxf(mxm, __shfl_xor(mxm, m2));
    if ((t & 63) == 0) sredf[0][w] = mxm;
    __syncthreads();
    mxm = sredf[0][0];
#pragma unroll
    for (int w2 = 1; w2 < 8; ++w2) mxm = fmaxf(mxm, sredf[0][w2]);

    float lov = mxm - 32.0f, hiv = mxm;
    {
        int par = 0;
#pragma unroll
        for (int it = 0; it < 12; ++it) {
            float mid = 0.5f * (lov + hiv);
            int cgt = 0;
#pragma unroll
            for (int j = 0; j < 32; ++j) {
                float v = ((mbits >> j) & 1) ? raw[j] : -3.0e38f;
                cgt += (v >= mid) ? 1 : 0;
            }
#pragma unroll
            for (int m2 = 1; m2 < 64; m2 <<= 1) cgt += __shfl_xor(cgt, m2);
            if ((t & 63) == 0) sredi[par][w] = cgt;
            __syncthreads();
            cgt = 0;
#pragma unroll
            for (int w2 = 0; w2 < 8; ++w2) cgt += sredi[par][w2];
            if (cgt >= k) lov = mid; else hiv = mid;
            par ^= 1;
        }
    }
    const float tv = lov;

    if (t == 0) { sIn = 0; sCand = 0; }
    __syncthreads();
    const float hiB = tv + DELTA, loB = tv - DELTA;
#pragma unroll
    for (int j = 0; j < 32; ++j) {
        int i = t + j * 512;
        float v = ((mbits >> j) & 1) ? raw[j] : -3.0e38f;
        if (v > hiB)       { int p = atomicAdd(&sIn, 1);   if (p < KCAP) idxWS[b * KCAP + p] = i; }
        else if (v >= loB) { int p = atomicAdd(&sCand, 1); if (p < CCAP) candIdx[b * CCAP + p] = i; }
    }

    float mx = -INFINITY;
#pragma unroll
    for (int j = 0; j < 32; ++j) mx = fmaxf(mx, raw[j]);
#pragma unroll
    for (int m2 = 1; m2 < 64; m2 <<= 1) mx = fmaxf(mx, __shfl_xor(mx, m2));
    __syncthreads();
    if ((t & 63) == 0) sredf[1][w] = mx;
    __syncthreads();
    mx = sredf[1][0];
#pragma unroll
    for (int w2 = 1; w2 < 8; ++w2) mx = fmaxf(mx, sredf[1][w2]);

    float sAll = 0.f, sM = 0.f;
#pragma unroll
    for (int j = 0; j < 32; ++j) {
        float e = __expf(raw[j] - mx);
        sAll += e;
        if ((mbits >> j) & 1) sM += e;
    }
#pragma unroll
    for (int m2 = 1; m2 < 64; m2 <<= 1) sAll += __shfl_xor(sAll, m2);
    __syncthreads();
    if ((t & 63) == 0) sredf[0][w] = sAll;
    __syncthreads();
    sAll = 0.f;
#pragma unroll
    for (int w2 = 0; w2 < 8; ++w2) sAll += sredf[0][w2];
#pragma unroll
    for (int m2 = 1; m2 < 64; m2 <<= 1) sM += __shfl_xor(sM, m2);
    __syncthreads();
    if ((t & 63) == 0) sredf[1][w] = sM;
    __syncthreads();
    sM = 0.f;
#pragma unroll
    for (int w2 = 0; w2 < 8; ++w2) sM += sredf[1][w2];

    const float inv = 1.0f / (sM + EPSV * sAll);
#pragma unroll
    for (int j = 0; j < 32; ++j) {
        int i = t + j * 512;
        float e = __expf(raw[j] - mx);
        Ab[i] = ((mbits >> j) & 1) ? e * inv : 0.0f;
    }
    if (t == 0) {
        int m1 = sIn;   if (m1 > k)    m1 = k;
        int cc = sCand; if (cc > CCAP) cc = CCAP;
        counts[b * 4]     = m1;
        counts[b * 4 + 1] = cc;
    }
}

// ---------------------------------------------------------------------------
// K3b (r15-verified, verbatim): 512 thr; thread = (d, ll-quarter).
// ---------------------------------------------------------------------------
__global__ __launch_bounds__(512)
void k3b_exact(const float* __restrict__ x,
               const float* __restrict__ Wv, const float* __restrict__ bv,
               const float* __restrict__ Wu, const float* __restrict__ bu,
               const float* __restrict__ Wa, const float* __restrict__ ba,
               const int* __restrict__ candIdx, const int* __restrict__ counts,
               float* __restrict__ candVal)
{
    __shared__ __align__(16) float sx[ROWB][LDIM];      // 16 KB
    __shared__ float sqv[4][ROWB][DDIM];                // 16 KB
    __shared__ float squ[4][ROWB][DDIM];                // 16 KB
    __shared__ float sred[2][ROWB];
    const int b = blockIdx.x;
    const int t = threadIdx.x;      // 0..511
    const int d = t & 127;
    const int q = t >> 7;           // 0..3
    const int cnt = counts[b * 4 + 1];
    const float ba0 = ba[0];

    for (int base = blockIdx.y * ROWB; base < cnt; base += gridDim.y * ROWB) {
        const int nr = min(ROWB, cnt - base);
#pragma unroll
        for (int rr = 0; rr < 2; ++rr) {
            int idx = t + rr * 512;
            int r   = idx >> 7;
            int c4  = idx & 127;
            int rowi = (r < nr) ? (base + r) : base;
            const int row = candIdx[b * CCAP + rowi];
            ((f32x4*)&sx[r][0])[c4] =
                ((const f32x4*)(x + ((size_t)b * NN + (size_t)row) * LDIM))[c4];
        }
        __syncthreads();

        float dv[ROWB], du[ROWB];
#pragma unroll
        for (int r = 0; r < ROWB; ++r) { dv[r] = 0.f; du[r] = 0.f; }
        const int ll0 = q * 128;
#pragma unroll 4
        for (int l2 = 0; l2 < 128; ++l2) {
            const int ll = ll0 + l2;
            const float wvl = Wv[ll * DDIM + d];
            const float wul = Wu[ll * DDIM + d];
#pragma unroll
            for (int r = 0; r < ROWB; ++r) {
                const float xv = sx[r][ll];
                dv[r] = fmaf(xv, wvl, dv[r]);
                du[r] = fmaf(xv, wul, du[r]);
            }
        }
#pragma unroll
        for (int r = 0; r < ROWB; ++r) { sqv[q][r][d] = dv[r]; squ[q][r][d] = du[r]; }
        __syncthreads();

        if (q == 0) {
            const float bvd = bv[d], bud = bu[d], wad = Wa[d];
            const int w2 = t >> 6;   // 0/1
#pragma unroll
            for (int r = 0; r < ROWB; ++r) {
                float fv = sqv[0][r][d] + sqv[1][r][d] + sqv[2][r][d] + sqv[3][r][d] + bvd;
                float fu = squ[0][r][d] + squ[1][r][d] + squ[2][r][d] + squ[3][r][d] + bud;
                float c = tanhf(fv) * (1.0f / (1.0f + expf(-fu))) * wad;
                c += __shfl_xor(c, 1);  c += __shfl_xor(c, 2);
                c += __shfl_xor(c, 4);  c += __shfl_xor(c, 8);
                c += __shfl_xor(c, 16); c += __shfl_xor(c, 32);
                if ((t & 63) == 0) sred[w2][r] = c;
            }
        }
        __syncthreads();
        if (t < nr) candVal[b * CCAP + base + t] = sred[0][t] + sred[1][t] + ba0;
        __syncthreads();
    }
}

// ---------------------------------------------------------------------------
// K34 (r15-verified, verbatim): 512 threads; coalesced pooling; split MLP.
// ---------------------------------------------------------------------------
__global__ __launch_bounds__(512)
void k34_select_final(const float* __restrict__ x, const int* __restrict__ kp,
                      const int* __restrict__ candIdx, const float* __restrict__ candVal,
                      const int* __restrict__ counts, const int* __restrict__ idxWS,
                      const float* __restrict__ W1, const float* __restrict__ b1,
                      const float* __restrict__ W2, const float* __restrict__ b2,
                      float* __restrict__ Yprob, float* __restrict__ Yhat)
{
    __shared__ u64 keys[CCAP];
    __shared__ int sIdx[KCAP];
    __shared__ int sFinal[KCAP];
    __shared__ int sPos;
    __shared__ float sPooled[LDIM];
    __shared__ float sHp[4][HIDD];
    __shared__ float sH[HIDD];
    __shared__ float sY[4];
    const int b = blockIdx.x;
    const int t = threadIdx.x;      // 0..511
    int k = get_k(kp); if (k > KCAP) k = KCAP;
    const int m1  = counts[b * 4];
    const int cnt = counts[b * 4 + 1];
    int need = k - m1; if (need < 0) need = 0; if (need > cnt) need = cnt;

    for (int i = t; i < cnt; i += 512)
        keys[i] = (((u64)okey(candVal[b * CCAP + i])) << 14)
                | (u64)(16383 - candIdx[b * CCAP + i]);
    if (t < m1) sIdx[t] = idxWS[b * KCAP + t];
    if (t == 0) sPos = 0;
    if (t < KCAP) sFinal[t] = 0;
    __syncthreads();
    for (int i = t; i < cnt; i += 512) {
        u64 mk = keys[i];
        int rank = 0;
        for (int j = 0; j < cnt; ++j) rank += (keys[j] > mk) ? 1 : 0;
        if (rank < need) { int p = atomicAdd(&sPos, 1); sIdx[m1 + p] = candIdx[b * CCAP + i]; }
    }
    __syncthreads();
    int tot = m1 + need; if (tot > k) tot = k;
    if (t < tot) {
        int myv = sIdx[t];
        int rank = 0;
        for (int e = 0; e < tot; ++e) rank += (sIdx[e] < myv) ? 1 : 0;
        sFinal[rank] = myv;
    }
    __syncthreads();

    {
        float a0 = 0.0f;
        int j = 0;
        for (; j + 8 <= k; j += 8) {
            float t0[8];
#pragma unroll
            for (int u2 = 0; u2 < 8; ++u2)
                t0[u2] = x[((size_t)b * NN + (size_t)sFinal[j + u2]) * LDIM + t];
#pragma unroll
            for (int u2 = 0; u2 < 8; ++u2) a0 += t0[u2];
        }
        for (; j < k; ++j)
            a0 += x[((size_t)b * NN + (size_t)sFinal[j]) * LDIM + t];
        sPooled[t] = a0 * (1.0f / (float)k);
    }
    __syncthreads();

    {
        const int d = t & 127;
        const int q = t >> 7;
        float acc = 0.f;
#pragma unroll 4
        for (int l2 = 0; l2 < 128; ++l2) {
            int ll = q * 128 + l2;
            acc = fmaf(sPooled[ll], W1[ll * HIDD + d], acc);
        }
        sHp[q][d] = acc;
    }
    __syncthreads();
    if (t < HIDD) {
        float acc = b1[t] + sHp[0][t] + sHp[1][t] + sHp[2][t] + sHp[3][t];
        sH[t] = fmaxf(acc, 0.0f);
    }
    __syncthreads();
    if (t < NCLS) {
        float y = b2[t];
        for (int hh = 0; hh < HIDD; ++hh) y = fmaf(sH[hh], W2[hh * NCLS + t], y);
        Yprob[b * NCLS + t] = y;
        sY[t] = y;
    }
    __syncthreads();
    if (t == 0) {
        int am = 0; float bst = sY[0];
        if (sY[1] > bst) { bst = sY[1]; am = 1; }
        if (sY[2] > bst) { bst = sY[2]; am = 2; }
        Yhat[b] = (float)am;
    }
}

// ---------------------------------------------------------------------------
extern "C" void kernel_launch(void* const* d_in, const int* in_sizes, int n_in,
                              void* d_out, int out_size, void* d_ws, size_t ws_size,
                              hipStream_t stream)
{
    const float* x    = (const float*)d_in[0];
    const float* mask = (const float*)d_in[1];
    const float* Wv   = (const float*)d_in[2];
    const float* bv   = (const float*)d_in[3];
    const float* Wu   = (const float*)d_in[4];
    const float* bu   = (const float*)d_in[5];
    const float* Wa   = (const float*)d_in[6];
    const float* ba   = (const float*)d_in[7];
    const float* W1   = (const float*)d_in[8];
    const float* b1   = (const float*)d_in[9];
    const float* W2   = (const float*)d_in[10];
    const float* b2   = (const float*)d_in[11];
    const int*   kp   = (const int*)d_in[12];

    float* out   = (float*)d_out;
    float* Yprob = out;        // [16,3] = 48
    float* Yhat  = out + 48;   // [16]
    float* A     = out + 64;   // [16,16384]  (logits first, softmax in-place)

    char* wsb = (char*)d_ws;
    unsigned short* Wp = (unsigned short*)wsb;        // 256 KB
    int*   idxWS   = (int*)  (wsb + 262144);
    int*   candIdx = (int*)  (wsb + 278528);
    float* candVal = (float*)(wsb + 344064);
    int*   counts  = (int*)  (wsb + 409600);

    k0_prep  <<<512, 256, 0, stream>>>(Wv, Wu, Wp);
    k1_mfma  <<<256, 512, 0, stream>>>(x, Wp, bv, bu, Wa, ba, A);
    k3a_band_softmax<<<NB, 512, 0, stream>>>(A, mask, kp, idxWS, candIdx, counts);
    k3b_exact<<<dim3(NB, 32), 512, 0, stream>>>(x, Wv, bv, Wu, bu, Wa, ba,
                                                candIdx, counts, candVal);
    k34_select_final<<<NB, 512, 0, stream>>>(x, kp, candIdx, candVal, counts, idxWS,
                                             W1, b1, W2, b2, Yprob, Yhat);
}